// Round 18
// baseline (1322.802 us; speedup 1.0000x reference)
//
#include <hip/hip_runtime.h>

// Semi-CRF log-partition. B=4, T=512, L=96, W=63.
// v18 = v17 barrier-lockstep finalizer widened to 640 thr (10 waves):
//   waves 0,1 CORE (d1 + merge {c2,c3,c4,REST} + publish)
//   waves 2,3 d2 (slot2(t+1) from ring[t-1]); 4,5 d3 (ring[t-2]);
//   waves 6,7 d4 NEW (ring[t-3]); 8,9 REST: chain ends d=5..12 + z,
//   depth-2 prefetch -> min external slack 4 steps (4r >= 2V+relay_iter).
// Relays: d=5..63, 3-way target split (t mod 3), 177 units, 5 units/block.
// bf16 alpha ring; f32 relay staging. Handoffs: 8B relaxed agent atomics
// (axp NaN sentinel, chain tag in low 8 mantissa bits of v).

#define Tn 512
#define Ln 96
#define HL 48
#define LSQ (Ln * Ln)
#define Wn 63
#define KCH 8
#define NROLE 37  // 1 finalizer + 36 relay roles (5 pair-units each) per batch
#define NEGINF (-1e30f)
#define SENT 0x7FC00000u

#define AGENT __HIP_MEMORY_SCOPE_AGENT
#define WG __HIP_MEMORY_SCOPE_WORKGROUP
#define RLX __ATOMIC_RELAXED
#define LDSF() asm volatile("s_waitcnt lgkmcnt(0)" ::: "memory")
#define CBAR() asm volatile("" ::: "memory")
#define BARRIER()                 \
  do {                            \
    LDSF();                       \
    CBAR();                       \
    __builtin_amdgcn_s_barrier(); \
    CBAR();                       \
  } while (0)
#define SIDX(b, i, t) ((((size_t)(b) * Tn + (i)) * Tn + (t)) * Ln)

typedef unsigned long long u64;
typedef unsigned int u32;
typedef unsigned short u16;

__device__ __forceinline__ float wsumred(float v) {
#pragma unroll
  for (int m = 32; m >= 1; m >>= 1) v += __shfl_xor(v, m, 64);
  return v;
}
__device__ __forceinline__ u64 pack2(float lo, float hi) {
  return (u64)__float_as_uint(lo) | ((u64)__float_as_uint(hi) << 32);
}
__device__ __forceinline__ u16 tobf16(float x) {
  return (u16)((__float_as_uint(x) + 0x8000u) >> 16);
}
__device__ __forceinline__ float wavemax48(float v) {
  int x;
  x = __builtin_amdgcn_update_dpp(__float_as_int(v), __float_as_int(v), 0xB1,
                                  0xF, 0xF, false);
  v = fmaxf(v, __int_as_float(x));
  x = __builtin_amdgcn_update_dpp(__float_as_int(v), __float_as_int(v), 0x4E,
                                  0xF, 0xF, false);
  v = fmaxf(v, __int_as_float(x));
  x = __builtin_amdgcn_update_dpp(__float_as_int(v), __float_as_int(v), 0x141,
                                  0xF, 0xF, false);
  v = fmaxf(v, __int_as_float(x));
  x = __builtin_amdgcn_update_dpp(__float_as_int(v), __float_as_int(v), 0x140,
                                  0xF, 0xF, false);
  v = fmaxf(v, __int_as_float(x));
  float r0 = __int_as_float(__builtin_amdgcn_readlane(__float_as_int(v), 0));
  float r1 = __int_as_float(__builtin_amdgcn_readlane(__float_as_int(v), 16));
  float r2 = __int_as_float(__builtin_amdgcn_readlane(__float_as_int(v), 32));
  float r3 = __int_as_float(__builtin_amdgcn_readlane(__float_as_int(v), 48));
  return fmaxf(fmaxf(r0, r1), fmaxf(r2, r3));
}
__device__ __forceinline__ float comb(float Slo, float Shi, float C0, float C1,
                                      float wseg) {
  const float Cm = fmaxf(C0, C1);
  return Cm + wseg + __logf(__expf(C0 - Cm) * Slo + __expf(C1 - Cm) * Shi);
}

// f32 matvec (relays): 24 ds_read_b128
#define MV1(SRC, RR, SLO, SHI)                                       \
  float SLO, SHI;                                                    \
  {                                                                  \
    const float4* A4 = (const float4*)(SRC);                         \
    float a0 = 0, a1 = 0, a2 = 0, a3 = 0;                            \
    _Pragma("unroll") for (int q = 0; q < 12; ++q) {                 \
      float4 a = A4[q];                                              \
      a0 = fmaf(a.x, RR[4 * q + 0], a0);                             \
      a1 = fmaf(a.y, RR[4 * q + 1], a1);                             \
      a2 = fmaf(a.z, RR[4 * q + 2], a2);                             \
      a3 = fmaf(a.w, RR[4 * q + 3], a3);                             \
    }                                                                \
    SLO = (a0 + a1) + (a2 + a3);                                     \
    float b0 = 0, b1 = 0, b2 = 0, b3 = 0;                            \
    _Pragma("unroll") for (int q = 12; q < 24; ++q) {                \
      float4 a = A4[q];                                              \
      b0 = fmaf(a.x, RR[4 * q + 0], b0);                             \
      b1 = fmaf(a.y, RR[4 * q + 1], b1);                             \
      b2 = fmaf(a.z, RR[4 * q + 2], b2);                             \
      b3 = fmaf(a.w, RR[4 * q + 3], b3);                             \
    }                                                                \
    SHI = (b0 + b1) + (b2 + b3);                                     \
  }

// bf16 matvec (finalizer): 12 ds_read_b128, shift/and unpack
#define MVB(SRC, RR, SLO, SHI)                                               \
  float SLO, SHI;                                                            \
  {                                                                          \
    const uint4* A4 = (const uint4*)(SRC);                                   \
    float a0 = 0, a1 = 0, a2 = 0, a3 = 0;                                    \
    _Pragma("unroll") for (int q = 0; q < 6; ++q) {                          \
      uint4 a = A4[q];                                                       \
      a0 = fmaf(__uint_as_float(a.x << 16), RR[8 * q + 0], a0);              \
      a1 = fmaf(__uint_as_float(a.x & 0xFFFF0000u), RR[8 * q + 1], a1);      \
      a2 = fmaf(__uint_as_float(a.y << 16), RR[8 * q + 2], a2);              \
      a3 = fmaf(__uint_as_float(a.y & 0xFFFF0000u), RR[8 * q + 3], a3);      \
      a0 = fmaf(__uint_as_float(a.z << 16), RR[8 * q + 4], a0);              \
      a1 = fmaf(__uint_as_float(a.z & 0xFFFF0000u), RR[8 * q + 5], a1);      \
      a2 = fmaf(__uint_as_float(a.w << 16), RR[8 * q + 6], a2);              \
      a3 = fmaf(__uint_as_float(a.w & 0xFFFF0000u), RR[8 * q + 7], a3);      \
    }                                                                        \
    SLO = (a0 + a1) + (a2 + a3);                                             \
    float b0 = 0, b1 = 0, b2 = 0, b3 = 0;                                    \
    _Pragma("unroll") for (int q = 6; q < 12; ++q) {                         \
      uint4 a = A4[q];                                                       \
      b0 = fmaf(__uint_as_float(a.x << 16), RR[8 * q + 0], b0);              \
      b1 = fmaf(__uint_as_float(a.x & 0xFFFF0000u), RR[8 * q + 1], b1);      \
      b2 = fmaf(__uint_as_float(a.y << 16), RR[8 * q + 2], b2);              \
      b3 = fmaf(__uint_as_float(a.y & 0xFFFF0000u), RR[8 * q + 3], b3);      \
      b0 = fmaf(__uint_as_float(a.z << 16), RR[8 * q + 4], b0);              \
      b1 = fmaf(__uint_as_float(a.z & 0xFFFF0000u), RR[8 * q + 5], b1);      \
      b2 = fmaf(__uint_as_float(a.w << 16), RR[8 * q + 6], b2);              \
      b3 = fmaf(__uint_as_float(a.w & 0xFFFF0000u), RR[8 * q + 7], b3);      \
    }                                                                        \
    SHI = (b0 + b1) + (b2 + b3);                                             \
  }

__global__ void init_ws(u64* ws) {
  const size_t n1 = (size_t)4 * Tn * Ln;
  const size_t n = n1 * 9;  // axp + 8 chains
  for (size_t i = (size_t)blockIdx.x * blockDim.x + threadIdx.x; i < n;
       i += (size_t)gridDim.x * blockDim.x)
    ws[i] = (i < n1) ? (((u64)SENT) << 32) : 0ull;
}

__global__ __launch_bounds__(640, 1) void semicrf(
    const float* __restrict__ seg, const float* __restrict__ tr,
    float* __restrict__ out, u64* axp, u64* acc) {
  const int b = blockIdx.x / NROLE;
  const int role = blockIdx.x % NROLE;
  const int tid = threadIdx.x;

  __shared__ __align__(16) float E[LSQ];           // exp(trans) 36 KB
  __shared__ __align__(16) u16 AlbRh[8][Ln];       // bf16 alpha ring
  __shared__ float CRng[8][2];                     // per-half C ring
  __shared__ __align__(16) float slotC2[4][Ln];    // d2 contributions
  __shared__ __align__(16) float slotC3[4][Ln];    // d3 contributions
  __shared__ __align__(16) float slotC4[4][Ln];    // d4 contributions
  __shared__ float RESTm[4][Ln];                   // chains+z merge (m)
  __shared__ float RESTv[4][Ln];                   // chains+z merge (v)
  __shared__ __align__(16) float Alb_s[5][2][Ln];  // relay staging (dbuf)
  __shared__ float CstS[5][2][2];
  __shared__ float redbuf[2];
  __shared__ int stg[5][2];

  if (tid < 10) stg[tid >> 1][tid & 1] = -1;
  for (int i = tid; i < LSQ; i += 640) E[i] = __expf(tr[i]);
  __syncthreads();  // init barrier (all 640 threads, every block)

  if (role != 0) {
    // == relay pair-unit: pu=(role-1)*5+pair -> d=5+pu/3, split m3=pu%3 ======
    const int pair = tid >> 7;  // 0..4
    const int tp = tid & 127;
    const int wv = tp >> 6;
    const int rl = tp & 63;
    const bool act = rl < HL;
    const int lab = wv * HL + (act ? rl : HL - 1);
    const int pu = (role - 1) * 5 + pair;  // 0..179
    if (pu >= 177) return;                 // after barrier: safe
    const int d = 5 + pu / 3;              // 5..63
    const int m3 = pu % 3;
    const int j = d & 7;
    u64* chain = acc + (size_t)(j * 4 + b) * Tn * Ln;
    const u64* axB = axp + (size_t)b * Tn * Ln;
    float R[Ln];
#pragma unroll
    for (int lp = 0; lp < Ln; ++lp) R[lp] = E[lp * Ln + lab];
    int wc = 1;
    const bool aHead = (d + KCH > Wn);
    const int t0 = d + ((m3 - (d % 3)) + 3) % 3;
    int bufi = 0;

    for (int t = t0; t < Tn; t += 3) {
      const int s = t - d;
      const int w = (t <= Wn) ? (s + 1) : (64 - d);
      while (w > wc) {
        ++wc;
#pragma unroll
        for (int lp = 0; lp < Ln; ++lp) R[lp] *= E[lp * Ln + lab];
      }
      const float segv = seg[SIDX(b, s + 1, t) + lab];
      const size_t tIdx = (size_t)t * Ln + lab;
      const bool head = aHead || (s < KCH);
      u64 ua = 0;
      if (!head) ua = __hip_atomic_load(&chain[tIdx], RLX, AGENT);

      u64 up = __hip_atomic_load(&axB[(size_t)s * Ln + lab], RLX, AGENT);
      while ((u32)(up >> 32) == SENT)
        up = __hip_atomic_load(&axB[(size_t)s * Ln + lab], RLX, AGENT);

      if (act) Alb_s[pair][bufi][lab] = __uint_as_float((u32)up);
      if (rl == 0) CstS[pair][bufi][wv] = __uint_as_float((u32)(up >> 32));
      LDSF();
      __hip_atomic_store(&stg[pair][wv], t, RLX, WG);
      while (__hip_atomic_load(&stg[pair][wv ^ 1], RLX, WG) < t) {}
      CBAR();
      const float C0 = CstS[pair][bufi][0], C1 = CstS[pair][bufi][1];
      MV1(Alb_s[pair][bufi], R, Slo, Shi)
      const float c = comb(Slo, Shi, C0, C1, (float)w * segv);
      bufi ^= 1;

      float m, v;
      if (head) {
        m = c;
        v = 1.f;
      } else {
        while (((ua >> 32) & 0xFFu) != (u32)(d + KCH))
          ua = __hip_atomic_load(&chain[tIdx], RLX, AGENT);
        const float pm = __uint_as_float((u32)ua);
        const float pv = __uint_as_float(((u32)(ua >> 32)) & ~0xFFu);
        const float nm = fmaxf(pm, c);
        v = pv * __expf(pm - nm) + __expf(c - nm);
        m = nm;
      }
      if (act) {
        const u32 vb = (__float_as_uint(v) & ~0xFFu) | (u32)d;
        __hip_atomic_store(&chain[tIdx],
                           (u64)__float_as_uint(m) | ((u64)vb << 32), RLX,
                           AGENT);
      }
    }
    return;
  }

  // ================== finalizer block: barrier lockstep ====================
  const int w10 = tid >> 6;  // 0..9
  const int l = tid & 63;
  const bool act = l < HL;
  const int h = w10 & 1;
  const int lab = h * HL + (act ? l : HL - 1);
  u64* axpB = axp + (size_t)b * Tn * Ln;
  const float bos = tr[LSQ + lab];

  if (w10 < 2) {
    // ------------------------------ CORE -----------------------------------
    float R1[Ln];
#pragma unroll
    for (int lp = 0; lp < Ln; ++lp) R1[lp] = E[lp * Ln + lab];
    int w1c = 1;
    float q0 = seg[SIDX(b, 1, 1) + lab];
    float q1 = seg[SIDX(b, 2, 2) + lab];
    {  // seed t=0: alpha0 = exp(seg[b,0,0,:]+bos) (reference stores exp'd)
      const float a0 = __expf(seg[SIDX(b, 0, 0) + lab] + bos);
      const float Cw = wavemax48(act ? a0 : NEGINF);
      const float ax0 = __expf(a0 - Cw);
      if (act) __hip_atomic_store(&axpB[lab], pack2(ax0, Cw), RLX, AGENT);
      if (act) AlbRh[0][lab] = tobf16(ax0);
      if (l == 0) CRng[0][h] = Cw;
    }
    BARRIER();

    float lastAx = 0.f, lastCw = 0.f;
    for (int t = 1; t < Tn; ++t) {
      const float s1 = q0;
      q0 = q1;
      if (t + 2 < Tn) q1 = seg[SIDX(b, t + 2, t + 2) + lab];
      const int w1 = (t <= Wn) ? t : Wn;
      if (w1 > w1c) {
        w1c = w1;
#pragma unroll
        for (int lp = 0; lp < Ln; ++lp) R1[lp] *= E[lp * Ln + lab];
      }
      const float C0 = CRng[(t - 1) & 7][0], C1 = CRng[(t - 1) & 7][1];
      MVB(AlbRh[(t - 1) & 7], R1, Slo, Shi)
      const float c1 = comb(Slo, Shi, C0, C1, (float)w1 * s1);
      const float c2 = (t >= 2) ? slotC2[t & 3][lab] : NEGINF;
      const float c3 = (t >= 3) ? slotC3[t & 3][lab] : NEGINF;
      const float c4 = (t >= 4) ? slotC4[t & 3][lab] : NEGINF;
      const float mr = RESTm[t & 3][lab], vr = RESTv[t & 3][lab];
      const float M =
          fmaxf(fmaxf(fmaxf(c1, c2), fmaxf(c3, c4)), mr);
      const float vs = __expf(c1 - M) + __expf(c2 - M) + __expf(c3 - M) +
                       __expf(c4 - M) + vr * __expf(mr - M);
      const float alpha = M + __logf(vs);
      const float Cw = wavemax48(act ? alpha : NEGINF);
      const float axn = __expf(alpha - Cw);
      if (act)
        __hip_atomic_store(&axpB[(size_t)t * Ln + lab], pack2(axn, Cw), RLX,
                           AGENT);
      if (act) AlbRh[t & 7][lab] = tobf16(axn);
      if (l == 0) CRng[t & 7][h] = Cw;
      lastAx = axn;
      lastCw = Cw;
      BARRIER();
    }
    const float sm = wsumred(act ? lastAx : 0.f);
    if (l == 0) redbuf[h] = lastCw + __logf(sm);
    BARRIER();
    if (w10 == 0 && l == 0) {
      const float G0 = redbuf[0], G1 = redbuf[1];
      const float Mx = fmaxf(G0, G1);
      out[b] = Mx + __logf(__expf(G0 - Mx) + __expf(G1 - Mx));
    }
    return;
  }

  if (w10 < 4) {
    // ------------------------------ d2 -------------------------------------
    float R2[Ln];
#pragma unroll
    for (int lp = 0; lp < Ln; ++lp) R2[lp] = E[lp * Ln + lab];
    int wc = 1;
    float q0 = seg[SIDX(b, 1, 2) + lab];  // tp1=2
    float q1 = seg[SIDX(b, 2, 3) + lab];  // tp1=3
    BARRIER();
    for (int t = 1; t < Tn; ++t) {
      const int tp1 = t + 1;
      if (tp1 < Tn) {
        const float sv = q0;
        q0 = q1;
        if (tp1 + 2 < Tn) q1 = seg[SIDX(b, tp1 + 1, tp1 + 2) + lab];
        const int w = (tp1 <= Wn) ? (tp1 - 1) : 62;
        if (w > wc) {
          wc = w;
#pragma unroll
          for (int lp = 0; lp < Ln; ++lp) R2[lp] *= E[lp * Ln + lab];
        }
        const float C0 = CRng[(t - 1) & 7][0], C1 = CRng[(t - 1) & 7][1];
        MVB(AlbRh[(t - 1) & 7], R2, Slo, Shi)
        const float c = comb(Slo, Shi, C0, C1, (float)w * sv);
        if (act) slotC2[tp1 & 3][lab] = c;
      }
      BARRIER();
    }
    BARRIER();
    return;
  }

  if (w10 < 6) {
    // ------------------------------ d3 -------------------------------------
    float R3[Ln];
#pragma unroll
    for (int lp = 0; lp < Ln; ++lp) R3[lp] = E[lp * Ln + lab];
    int wc = 1;
    float q0 = 0.f;                       // tp1=2 (unused)
    float q1 = seg[SIDX(b, 1, 3) + lab];  // tp1=3
    BARRIER();
    for (int t = 1; t < Tn; ++t) {
      const int tp1 = t + 1;
      if (tp1 < Tn) {
        const float sv = q0;
        q0 = q1;
        if (tp1 + 2 < Tn) q1 = seg[SIDX(b, tp1, tp1 + 2) + lab];
        if (tp1 >= 3) {
          const int w = (tp1 <= Wn) ? (tp1 - 2) : 61;
          if (w > wc) {
            wc = w;
#pragma unroll
            for (int lp = 0; lp < Ln; ++lp) R3[lp] *= E[lp * Ln + lab];
          }
          const float C0 = CRng[(t - 2) & 7][0], C1 = CRng[(t - 2) & 7][1];
          MVB(AlbRh[(t - 2) & 7], R3, Slo, Shi)
          const float c = comb(Slo, Shi, C0, C1, (float)w * sv);
          if (act) slotC3[tp1 & 3][lab] = c;
        }
      }
      BARRIER();
    }
    BARRIER();
    return;
  }

  if (w10 < 8) {
    // ------------------------------ d4 (NEW) --------------------------------
    float R4[Ln];
#pragma unroll
    for (int lp = 0; lp < Ln; ++lp) R4[lp] = E[lp * Ln + lab];
    int wc = 1;
    float q0 = 0.f;                       // tp1=3 (unused)
    float q1 = seg[SIDX(b, 1, 4) + lab];  // tp1=4
    BARRIER();
    BARRIER();  // consume step t=1's barrier pattern start
    // NOTE: loop below runs t=2..Tn-1 with its own barriers; we consumed the
    // first loop barrier above so counts line up: core does Tn-1 loop barriers
    // (t=1..511) + 1 final; we must match: 1 (above, t=1) + (t=2..511) + final.
    for (int t = 2; t < Tn; ++t) {
      const int tp1 = t + 1;
      if (tp1 < Tn) {
        const float sv = q0;
        q0 = q1;
        if (tp1 + 2 < Tn) q1 = seg[SIDX(b, tp1 - 2, tp1 + 2) + lab];
        if (tp1 >= 4) {
          const int w = (tp1 <= Wn) ? (tp1 - 3) : 60;
          if (w > wc) {
            wc = w;
#pragma unroll
            for (int lp = 0; lp < Ln; ++lp) R4[lp] *= E[lp * Ln + lab];
          }
          const float C0 = CRng[(t - 3) & 7][0], C1 = CRng[(t - 3) & 7][1];
          MVB(AlbRh[(t - 3) & 7], R4, Slo, Shi)
          const float c = comb(Slo, Shi, C0, C1, (float)w * sv);
          if (act) slotC4[tp1 & 3][lab] = c;
        }
      }
      BARRIER();
    }
    BARRIER();
    return;
  }

  {
    // ------------------------------ REST ------------------------------------
    const int endd[8] = {8, 9, 10, 11, 12, 5, 6, 7};  // min d per residue
    u64 UA[8], UB[8];
#pragma unroll
    for (int jj = 0; jj < 8; ++jj) {
      UA[jj] = 0;
      UB[jj] = 0;
    }
    float zq0 = seg[SIDX(b, 0, 2) + lab];  // z(2)
    float zq1 = seg[SIDX(b, 0, 3) + lab];  // z(3)
    {  // seed: REST(1) = z(1) only
      const float zv = 2.f * (seg[SIDX(b, 0, 1) + lab] + bos);
      if (act) {
        RESTm[1][lab] = zv;
        RESTv[1][lab] = 1.f;
      }
    }
    BARRIER();

#define RESTSTEP(U)                                                          \
  {                                                                          \
    float M = zv;                                                            \
    float em[8], ev[8];                                                      \
    _Pragma("unroll") for (int jj = 0; jj < 8; ++jj) {                       \
      if (tp1 >= endd[jj]) {                                                 \
        const size_t aIdx = (((size_t)jj * 4 + b) * Tn + tp1) * Ln + lab;    \
        while (((U[jj] >> 32) & 0xFFu) != (u32)endd[jj])                     \
          U[jj] = __hip_atomic_load(&acc[aIdx], RLX, AGENT);                 \
        em[jj] = __uint_as_float((u32)U[jj]);                                \
        ev[jj] = __uint_as_float(((u32)(U[jj] >> 32)) & ~0xFFu);             \
        M = fmaxf(M, em[jj]);                                                \
      } else {                                                               \
        em[jj] = NEGINF;                                                     \
        ev[jj] = 0.f;                                                        \
      }                                                                      \
    }                                                                        \
    float vs = __expf(zv - M);                                               \
    _Pragma("unroll") for (int jj = 0; jj < 8; ++jj) vs +=                   \
        ev[jj] * __expf(em[jj] - M);                                         \
    if (act) {                                                               \
      RESTm[tp1 & 3][lab] = M;                                               \
      RESTv[tp1 & 3][lab] = vs;                                              \
    }                                                                        \
    if (tp1 + 2 < Tn) {                                                      \
      _Pragma("unroll") for (int jj = 0; jj < 8; ++jj) {                     \
        if (tp1 + 2 >= endd[jj])                                             \
          U[jj] = __hip_atomic_load(                                         \
              &acc[(((size_t)jj * 4 + b) * Tn + (tp1 + 2)) * Ln + lab], RLX, \
              AGENT);                                                        \
      }                                                                      \
    }                                                                        \
  }

    for (int t = 1; t < Tn; ++t) {
      const int tp1 = t + 1;
      if (tp1 < Tn) {
        const float zv = (tp1 <= Wn) ? (float)(tp1 + 1) * (zq0 + bos) : NEGINF;
        zq0 = zq1;
        if (tp1 + 2 <= Wn) zq1 = seg[SIDX(b, 0, tp1 + 2) + lab];
        if (tp1 & 1) {
          RESTSTEP(UA)
        } else {
          RESTSTEP(UB)
        }
      }
      BARRIER();
    }
    BARRIER();
    return;
  }
}

extern "C" void kernel_launch(void* const* d_in, const int* in_sizes, int n_in,
                              void* d_out, int out_size, void* d_ws,
                              size_t ws_size, hipStream_t stream) {
  const float* seg = (const float*)d_in[0];  // (4,512,512,96) f32
  const float* tr = (const float*)d_in[1];   // (97,96) f32
  float* out = (float*)d_out;                // (4,) f32

  u64* axp = (u64*)d_ws;                 // [4][512][96]
  u64* acc = axp + (size_t)4 * Tn * Ln;  // [8][4][512][96]

  hipLaunchKernelGGL(init_ws, dim3(2048), dim3(256), 0, stream, (u64*)d_ws);
  hipLaunchKernelGGL(semicrf, dim3(4 * NROLE), dim3(640), 0, stream, seg, tr,
                     out, axp, acc);
}